// Round 4
// baseline (4675.489 us; speedup 1.0000x reference)
//
#include <hip/hip_runtime.h>
#include <hip/hip_bf16.h>

#define NHEAD 16
#define DHEAD 64
#define DMODEL 1024
#define QLEN 1024
#define MEMLEN 1024
#define BSZ 2
#define KLEN 2048
#define LN_EPS 1e-5f

// C[M,N] (f32) = A[M,K] (f32) @ B[K,N] (f32)
// A row m: m < split -> A0 + m*K ; else A1 + (m-split)*K  (virtual concat)
__global__ __launch_bounds__(256)
void gemm_f32(const float* __restrict__ A0, const float* __restrict__ A1, int split,
              const float* __restrict__ B, float* __restrict__ C,
              int M, int N, int K) {
    __shared__ float As[16][65];  // [k][m]
    __shared__ float Bs[16][65];  // [k][n]
    const int t = threadIdx.x;
    const int bm = blockIdx.x * 64, bn = blockIdx.y * 64;
    const int tm = (t >> 4) * 4, tn = (t & 15) * 4;
    float acc[4][4] = {};
    for (int k0 = 0; k0 < K; k0 += 16) {
        #pragma unroll
        for (int e = 0; e < 4; e++) {
            int li = t * 4 + e;
            int ml = li >> 4, kl = li & 15;
            int m = bm + ml;
            const float* Arow = (m < split) ? (A0 + (size_t)m * K)
                                            : (A1 + (size_t)(m - split) * K);
            As[kl][ml] = Arow[k0 + kl];
            int kl2 = li >> 6, nl = li & 63;
            Bs[kl2][nl] = B[(size_t)(k0 + kl2) * N + bn + nl];
        }
        __syncthreads();
        #pragma unroll
        for (int k = 0; k < 16; k++) {
            float a[4], bb[4];
            #pragma unroll
            for (int x = 0; x < 4; x++) a[x] = As[k][tm + x];
            #pragma unroll
            for (int x = 0; x < 4; x++) bb[x] = Bs[k][tn + x];
            #pragma unroll
            for (int y = 0; y < 4; y++)
                #pragma unroll
                for (int x = 0; x < 4; x++)
                    acc[y][x] = fmaf(a[y], bb[x], acc[y][x]);
        }
        __syncthreads();
    }
    #pragma unroll
    for (int y = 0; y < 4; y++)
        #pragma unroll
        for (int x = 0; x < 4; x++)
            C[(size_t)(bm + tm + y) * N + bn + tn + x] = acc[y][x];
}

// One block per (query i, batch b, head n). 256 threads (4 waves).
// w_heads layout: [klen*bsz rows = j*2+b, 3072]; q cols [0,1024), k [1024,2048), v [2048,3072)
// q row for query i, batch b: m = 2048 + i*2 + b
// rel_shift: score[i][j] uses BD_raw[i][j + QLEN-1-i]; pad/wrap entries are provably masked.
__global__ __launch_bounds__(256)
void attn_kernel(const float* __restrict__ w_heads, const float* __restrict__ r_head_k,
                 const float* __restrict__ r_w_bias, const float* __restrict__ r_r_bias,
                 float* __restrict__ attn_vec) {
    const int i = blockIdx.x, b = blockIdx.y, n = blockIdx.z;
    const int t = threadIdx.x;
    __shared__ float qw[64], qr[64];
    __shared__ float p[KLEN];
    __shared__ float red[4];
    __shared__ float opart[4][64];

    if (t < 64) {
        float qv = w_heads[(size_t)(2048 + i * 2 + b) * 3072 + n * 64 + t];
        qw[t] = qv + r_w_bias[n * 64 + t];
        qr[t] = qv + r_r_bias[n * 64 + t];
    }
    __syncthreads();

    const int jmax = i + MEMLEN;        // inclusive upper bound of visible keys
    const int rbase = QLEN - 1 - i;     // rel-shift offset
    float lmax = -1e30f;
    for (int jb = 0; jb < KLEN; jb += 256) {
        int j = jb + t;
        float s = -1e30f;
        if (j <= jmax) {
            const float* krow = w_heads + (size_t)(j * 2 + b) * 3072 + 1024 + n * 64;
            const float* rrow = r_head_k + (size_t)(j + rbase) * 1024 + n * 64;
            float ac = 0.f, bd = 0.f;
            #pragma unroll 8
            for (int d = 0; d < 64; d++) {
                ac = fmaf(qw[d], krow[d], ac);
                bd = fmaf(qr[d], rrow[d], bd);
            }
            s = (ac + bd) * 0.125f;
        }
        p[j] = s;
        lmax = fmaxf(lmax, s);
    }
    #pragma unroll
    for (int off = 32; off; off >>= 1) lmax = fmaxf(lmax, __shfl_xor(lmax, off));
    if ((t & 63) == 0) red[t >> 6] = lmax;
    __syncthreads();
    lmax = fmaxf(fmaxf(red[0], red[1]), fmaxf(red[2], red[3]));

    float lsum = 0.f;
    for (int jb = 0; jb < KLEN; jb += 256) {
        int j = jb + t;
        float e = (j <= jmax) ? __expf(p[j] - lmax) : 0.f;
        p[j] = e;
        lsum += e;
    }
    #pragma unroll
    for (int off = 32; off; off >>= 1) lsum += __shfl_xor(lsum, off);
    __syncthreads();  // all reads of red (max) done before rewrite
    if ((t & 63) == 0) red[t >> 6] = lsum;
    __syncthreads();
    const float inv = 1.f / (red[0] + red[1] + red[2] + red[3]);

    // PV: thread t owns d = t&63, j-stripe t>>6 (step 4). v reads coalesced.
    const int d = t & 63, s4 = t >> 6;
    float o = 0.f;
    for (int j = s4; j <= jmax; j += 4)
        o = fmaf(p[j], w_heads[(size_t)(j * 2 + b) * 3072 + 2048 + n * 64 + d], o);
    opart[s4][d] = o;
    __syncthreads();
    if (t < 64) {
        float oo = (opart[0][t] + opart[1][t] + opart[2][t] + opart[3][t]) * inv;
        attn_vec[(size_t)(i * 2 + b) * 1024 + n * 64 + t] = oo;
    }
}

// One block (256 threads) per output row m (= i*2+b). out = LN(w + attn_vec @ W_o)
// OUTPUT IS FLOAT32 (reference returns f32; harness decodes f32).
__global__ __launch_bounds__(256)
void outproj_ln(const float* __restrict__ attn_vec, const float* __restrict__ W_o,
                const float* __restrict__ w, const float* __restrict__ gamma,
                const float* __restrict__ beta, float* __restrict__ out) {
    const int m = blockIdx.x;
    const int t = threadIdx.x;
    __shared__ float av[DMODEL];
    __shared__ float red[256];
    #pragma unroll
    for (int e = 0; e < 4; e++) av[t + e * 256] = attn_vec[(size_t)m * DMODEL + t + e * 256];
    __syncthreads();
    float acc[4] = {0.f, 0.f, 0.f, 0.f};
    for (int k = 0; k < DMODEL; k++) {
        float a = av[k];
        #pragma unroll
        for (int e = 0; e < 4; e++)
            acc[e] = fmaf(a, W_o[(size_t)k * DMODEL + e * 256 + t], acc[e]);
    }
    float x[4];
    #pragma unroll
    for (int e = 0; e < 4; e++)
        x[e] = acc[e] + w[(size_t)m * DMODEL + e * 256 + t];

    float s = x[0] + x[1] + x[2] + x[3];
    red[t] = s;
    __syncthreads();
    #pragma unroll
    for (int off = 128; off; off >>= 1) {
        if (t < off) red[t] += red[t + off];
        __syncthreads();
    }
    const float mu = red[0] * (1.f / 1024.f);
    __syncthreads();
    float s2 = 0.f;
    #pragma unroll
    for (int e = 0; e < 4; e++) { float dx = x[e] - mu; s2 += dx * dx; }
    red[t] = s2;
    __syncthreads();
    #pragma unroll
    for (int off = 128; off; off >>= 1) {
        if (t < off) red[t] += red[t + off];
        __syncthreads();
    }
    const float rstd = rsqrtf(red[0] * (1.f / 1024.f) + LN_EPS);
    #pragma unroll
    for (int e = 0; e < 4; e++) {
        int c = e * 256 + t;
        float y = (x[e] - mu) * rstd * gamma[c] + beta[c];
        out[(size_t)m * DMODEL + c] = y;   // f32 store
    }
}

extern "C" void kernel_launch(void* const* d_in, const int* in_sizes, int n_in,
                              void* d_out, int out_size, void* d_ws, size_t ws_size,
                              hipStream_t stream) {
    const float* w        = (const float*)d_in[0];
    const float* r        = (const float*)d_in[1];
    const float* r_w_bias = (const float*)d_in[2];
    const float* r_r_bias = (const float*)d_in[3];
    const float* mems     = (const float*)d_in[4];
    // d_in[5] attn_mask: deterministic (j <= i+MEMLEN), applied analytically
    const float* W_qkv    = (const float*)d_in[6];
    const float* W_r      = (const float*)d_in[7];
    const float* W_o      = (const float*)d_in[8];
    const float* gamma    = (const float*)d_in[9];
    const float* beta     = (const float*)d_in[10];
    float* out = (float*)d_out;

    float* w_heads  = (float*)d_ws;                         // [4096, 3072] f32
    float* r_head_k = w_heads + (size_t)4096 * 3072;        // [2048, 1024] f32
    float* attn_vec = r_head_k + (size_t)2048 * 1024;       // [2048, 1024] f32

    dim3 b256(256);
    // cat(mems, w) @ W_qkv : M=4096 (rows j*2+b), K=1024, N=3072
    gemm_f32<<<dim3(4096 / 64, 3072 / 64), b256, 0, stream>>>(
        mems, w, 2048, W_qkv, w_heads, 4096, 3072, 1024);
    // r @ W_r : M=2048, K=1024, N=1024
    gemm_f32<<<dim3(2048 / 64, 1024 / 64), b256, 0, stream>>>(
        r, r, 1 << 30, W_r, r_head_k, 2048, 1024, 1024);
    attn_kernel<<<dim3(QLEN, BSZ, NHEAD), b256, 0, stream>>>(
        w_heads, r_head_k, r_w_bias, r_r_bias, attn_vec);
    outproj_ln<<<dim3(QLEN * BSZ), b256, 0, stream>>>(
        attn_vec, W_o, w, gamma, beta, out);
}

// Round 5
// 1153.155 us; speedup vs baseline: 4.0545x; 4.0545x over previous
//
#include <hip/hip_runtime.h>
#include <hip/hip_bf16.h>

#define NHEAD 16
#define DHEAD 64
#define DMODEL 1024
#define QLEN 1024
#define MEMLEN 1024
#define BSZ 2
#define KLEN 2048
#define LN_EPS 1e-5f

typedef __hip_bfloat16 bf16;
typedef __attribute__((ext_vector_type(8))) short short8;
typedef __attribute__((ext_vector_type(4))) float f32x4;

__device__ __forceinline__ bf16 f2b(float x) { return __float2bfloat16(x); }
__device__ __forceinline__ short f2bs(float f) {
    bf16 h = __float2bfloat16(f);
    return *reinterpret_cast<short*>(&h);
}

#define MFMA16(a, b, c) __builtin_amdgcn_mfma_f32_16x16x32_bf16(a, b, c, 0, 0, 0)

// ---------------- QKV projection ----------------
// cat(mems,w)[4096,1024](f32) @ W_qkv[1024,3072](f32).
// Epilogue: cols [0,1024) -> Qw=bf16(q+r_w_bias), Qr=bf16(q+r_r_bias) (rows m>=2048 only,
// stored at m-2048 = i*2+b); [1024,2048) -> Kb bf16; [2048,3072) -> Vb bf16. Row m = j*2+b.
__global__ __launch_bounds__(256)
void gemm_qkv(const float* __restrict__ A0, const float* __restrict__ A1,
              const float* __restrict__ B,
              const float* __restrict__ rwb, const float* __restrict__ rrb,
              bf16* __restrict__ Qw, bf16* __restrict__ Qr,
              bf16* __restrict__ Kb, bf16* __restrict__ Vb) {
    const int K = 1024, N = 3072;
    __shared__ float As[16][65];
    __shared__ float Bs[16][65];
    const int t = threadIdx.x;
    const int bm = blockIdx.x * 64, bn = blockIdx.y * 64;
    const int tm = (t >> 4) * 4, tn = (t & 15) * 4;
    float acc[4][4] = {};
    for (int k0 = 0; k0 < K; k0 += 16) {
        #pragma unroll
        for (int e = 0; e < 4; e++) {
            int li = t * 4 + e;
            int ml = li >> 4, kl = li & 15;
            int m = bm + ml;
            const float* Arow = (m < 2048) ? (A0 + (size_t)m * K)
                                           : (A1 + (size_t)(m - 2048) * K);
            As[kl][ml] = Arow[k0 + kl];
            int kl2 = li >> 6, nl = li & 63;
            Bs[kl2][nl] = B[(size_t)(k0 + kl2) * N + bn + nl];
        }
        __syncthreads();
        #pragma unroll
        for (int k = 0; k < 16; k++) {
            float a[4], bb[4];
            #pragma unroll
            for (int x = 0; x < 4; x++) a[x] = As[k][tm + x];
            #pragma unroll
            for (int x = 0; x < 4; x++) bb[x] = Bs[k][tn + x];
            #pragma unroll
            for (int y = 0; y < 4; y++)
                #pragma unroll
                for (int x = 0; x < 4; x++)
                    acc[y][x] = fmaf(a[y], bb[x], acc[y][x]);
        }
        __syncthreads();
    }
    const int seg = bn >> 10, cb = (bn & 1023) + tn;
    #pragma unroll
    for (int y = 0; y < 4; y++) {
        int m = bm + tm + y;
        #pragma unroll
        for (int x = 0; x < 4; x++) {
            float v = acc[y][x];
            int c = cb + x;
            if (seg == 0) {
                if (m >= 2048) {
                    size_t o = (size_t)(m - 2048) * 1024 + c;
                    Qw[o] = f2b(v + rwb[c]);
                    Qr[o] = f2b(v + rrb[c]);
                }
            } else if (seg == 1) Kb[(size_t)m * 1024 + c] = f2b(v);
            else                 Vb[(size_t)m * 1024 + c] = f2b(v);
        }
    }
}

// ---------------- r @ W_r -> Rk bf16 [2048,1024] ----------------
__global__ __launch_bounds__(256)
void gemm_r(const float* __restrict__ A, const float* __restrict__ B,
            bf16* __restrict__ C) {
    const int K = 1024, N = 1024;
    __shared__ float As[16][65];
    __shared__ float Bs[16][65];
    const int t = threadIdx.x;
    const int bm = blockIdx.x * 64, bn = blockIdx.y * 64;
    const int tm = (t >> 4) * 4, tn = (t & 15) * 4;
    float acc[4][4] = {};
    for (int k0 = 0; k0 < K; k0 += 16) {
        #pragma unroll
        for (int e = 0; e < 4; e++) {
            int li = t * 4 + e;
            int ml = li >> 4, kl = li & 15;
            As[kl][ml] = A[(size_t)(bm + ml) * K + k0 + kl];
            int kl2 = li >> 6, nl = li & 63;
            Bs[kl2][nl] = B[(size_t)(k0 + kl2) * N + bn + nl];
        }
        __syncthreads();
        #pragma unroll
        for (int k = 0; k < 16; k++) {
            float a[4], bb[4];
            #pragma unroll
            for (int x = 0; x < 4; x++) a[x] = As[k][tm + x];
            #pragma unroll
            for (int x = 0; x < 4; x++) bb[x] = Bs[k][tn + x];
            #pragma unroll
            for (int y = 0; y < 4; y++)
                #pragma unroll
                for (int x = 0; x < 4; x++)
                    acc[y][x] = fmaf(a[y], bb[x], acc[y][x]);
        }
        __syncthreads();
    }
    #pragma unroll
    for (int y = 0; y < 4; y++)
        #pragma unroll
        for (int x = 0; x < 4; x++)
            C[(size_t)(bm + tm + y) * N + bn + tn + x] = f2b(acc[y][x]);
}

// ---------------- V transpose: Vb[j*2+b][d] -> Vt[(d*2+b)][j] ----------------
__global__ __launch_bounds__(256)
void transpose_v(const bf16* __restrict__ Vb, bf16* __restrict__ Vt) {
    __shared__ bf16 T[64][65];
    const int J0 = blockIdx.x * 64, D0 = blockIdx.y * 64, b = blockIdx.z;
    const int t = threadIdx.x;
    #pragma unroll
    for (int e = 0; e < 16; e++) {
        int flat = e * 256 + t;
        int jl = flat >> 6, dl = flat & 63;
        T[jl][dl] = Vb[(size_t)((J0 + jl) * 2 + b) * 1024 + D0 + dl];
    }
    __syncthreads();
    #pragma unroll
    for (int e = 0; e < 16; e++) {
        int flat = e * 256 + t;
        int dl = flat >> 6, jl = flat & 63;
        Vt[(size_t)((D0 + dl) * 2 + b) * 2048 + J0 + jl] = T[jl][dl];
    }
}

// ---------------- MFMA flash attention ----------------
// Block = (64-query tile I0, b, head n); wave w owns q rows [qbase, qbase+16).
// Barrier-free: each wave uses a private LDS slice.
// A-frag layout: A[m=lane&15][k=quad*8+j]; B-frag: B[k=quad*8+j][n=lane&15];
// C/D: col=lane&15, row=quad*4+reg.
__global__ __launch_bounds__(256)
void attn_mfma(const bf16* __restrict__ Qw, const bf16* __restrict__ Qr,
               const bf16* __restrict__ Kb, const bf16* __restrict__ Vt,
               const bf16* __restrict__ Rk, float* __restrict__ attn_vec) {
    const int I0 = blockIdx.x * 64, b = blockIdx.y, n = blockIdx.z;
    const int tid = threadIdx.x;
    const int w = tid >> 6, lane = tid & 63;
    const int quad = lane >> 4, l16 = lane & 15;
    const int qbase = I0 + 16 * w;

    __shared__ float Wl_s[4][16 * 80];   // rel-shift window tiles, per wave
    __shared__ float Pl_s[4][16 * 68];   // P round-trip (pad 64->68), per wave
    float* Wl = Wl_s[w];
    float* Pl = Pl_s[w];

    // Persistent Q A-fragments (k chunks d=0..31, 32..63)
    short8 aqw[2], aqr[2];
    {
        const bf16* qp = Qw + ((size_t)(qbase + l16) * 2 + b) * 1024 + n * 64 + quad * 8;
        aqw[0] = *reinterpret_cast<const short8*>(qp);
        aqw[1] = *reinterpret_cast<const short8*>(qp + 32);
        const bf16* qp2 = Qr + ((size_t)(qbase + l16) * 2 + b) * 1024 + n * 64 + quad * 8;
        aqr[0] = *reinterpret_cast<const short8*>(qp2);
        aqr[1] = *reinterpret_cast<const short8*>(qp2 + 32);
    }

    f32x4 O[4];
    #pragma unroll
    for (int d = 0; d < 4; d++) O[d] = (f32x4){0.f, 0.f, 0.f, 0.f};
    float m_r[4], l_r[4];
    #pragma unroll
    for (int r = 0; r < 4; r++) { m_r[r] = -1e30f; l_r[r] = 0.f; }

    const int Jmax = qbase + 15 + MEMLEN;   // last visible key for this wave
    for (int J0 = 0; J0 <= Jmax; J0 += 64) {
        // ---- BD window GEMM: W[16][80], rl -> Rk row Rw0+rl ----
        const int Rw0 = J0 - qbase + 1008;  // = (J0+col) + 1023 - (qbase+row) - (col-row+15)
        #pragma unroll
        for (int s = 0; s < 5; s++) {
            int rrow = Rw0 + 16 * s + l16;
            short8 b0 = (short8){0,0,0,0,0,0,0,0}, b1 = b0;
            if (rrow < 2048) {   // rrow >= 0 always; rows >=2048 map only to masked pairs
                const bf16* rp = Rk + (size_t)rrow * 1024 + n * 64 + quad * 8;
                b0 = *reinterpret_cast<const short8*>(rp);
                b1 = *reinterpret_cast<const short8*>(rp + 32);
            }
            f32x4 acc = (f32x4){0.f, 0.f, 0.f, 0.f};
            acc = MFMA16(aqr[0], b0, acc);
            acc = MFMA16(aqr[1], b1, acc);
            #pragma unroll
            for (int r = 0; r < 4; r++)
                Wl[(quad * 4 + r) * 80 + 16 * s + l16] = acc[r];
        }

        // ---- AC GEMM + score assembly ----
        float sv[4][4];   // [n16][r]
        #pragma unroll
        for (int n16 = 0; n16 < 4; n16++) {
            int key = J0 + 16 * n16 + l16;
            const bf16* kp = Kb + ((size_t)key * 2 + b) * 1024 + n * 64 + quad * 8;
            short8 k0 = *reinterpret_cast<const short8*>(kp);
            short8 k1 = *reinterpret_cast<const short8*>(kp + 32);
            f32x4 acc = (f32x4){0.f, 0.f, 0.f, 0.f};
            acc = MFMA16(aqw[0], k0, acc);
            acc = MFMA16(aqw[1], k1, acc);
            #pragma unroll
            for (int r = 0; r < 4; r++) {
                int row = quad * 4 + r, col = 16 * n16 + l16;
                float s = (acc[r] + Wl[row * 80 + col - row + 15]) * 0.125f;
                if (J0 + col > qbase + row + MEMLEN) s = -1e30f;  // causal+mem mask
                sv[n16][r] = s;
            }
        }

        // ---- online softmax (per row; 16-lane shfl reductions) ----
        float alpha[4];
        #pragma unroll
        for (int r = 0; r < 4; r++) {
            float mx = fmaxf(fmaxf(sv[0][r], sv[1][r]), fmaxf(sv[2][r], sv[3][r]));
            #pragma unroll
            for (int msk = 1; msk < 16; msk <<= 1) mx = fmaxf(mx, __shfl_xor(mx, msk));
            float mn = fmaxf(m_r[r], mx);
            alpha[r] = __expf(m_r[r] - mn);
            m_r[r] = mn;
            float rs = 0.f;
            #pragma unroll
            for (int n16 = 0; n16 < 4; n16++) {
                float p = __expf(sv[n16][r] - mn);
                sv[n16][r] = p;
                rs += p;
            }
            #pragma unroll
            for (int msk = 1; msk < 16; msk <<= 1) rs += __shfl_xor(rs, msk);
            l_r[r] = l_r[r] * alpha[r] + rs;
        }

        // ---- P -> LDS (C-layout), rescale O ----
        #pragma unroll
        for (int n16 = 0; n16 < 4; n16++)
            #pragma unroll
            for (int r = 0; r < 4; r++)
                Pl[(quad * 4 + r) * 68 + 16 * n16 + l16] = sv[n16][r];
        #pragma unroll
        for (int d = 0; d < 4; d++)
            #pragma unroll
            for (int r = 0; r < 4; r++)
                O[d][r] *= alpha[r];

        // ---- read P as A-frags (bf16) ----
        short8 ap[2];
        #pragma unroll
        for (int kc = 0; kc < 2; kc++) {
            short8 v;
            #pragma unroll
            for (int j = 0; j < 8; j++)
                v[j] = f2bs(Pl[l16 * 68 + kc * 32 + quad * 8 + j]);
            ap[kc] = v;
        }

        // ---- PV ----
        #pragma unroll
        for (int ds = 0; ds < 4; ds++) {
            const bf16* vp = Vt + ((size_t)(n * 64 + 16 * ds + l16) * 2 + b) * 2048
                             + J0 + quad * 8;
            short8 v0 = *reinterpret_cast<const short8*>(vp);
            short8 v1 = *reinterpret_cast<const short8*>(vp + 32);
            O[ds] = MFMA16(ap[0], v0, O[ds]);
            O[ds] = MFMA16(ap[1], v1, O[ds]);
        }
    }

    // ---- epilogue: O/l -> attn_vec (f32) ----
    #pragma unroll
    for (int ds = 0; ds < 4; ds++)
        #pragma unroll
        for (int r = 0; r < 4; r++) {
            int q = qbase + quad * 4 + r;
            attn_vec[((size_t)q * 2 + b) * 1024 + n * 64 + 16 * ds + l16] =
                O[ds][r] / l_r[r];
        }
}

// ---------------- out = LN(w + attn_vec @ W_o), f32 store ----------------
__global__ __launch_bounds__(256)
void outproj_ln(const float* __restrict__ attn_vec, const float* __restrict__ W_o,
                const float* __restrict__ w, const float* __restrict__ gamma,
                const float* __restrict__ beta, float* __restrict__ out) {
    const int m = blockIdx.x;
    const int t = threadIdx.x;
    __shared__ float av[DMODEL];
    __shared__ float red[256];
    #pragma unroll
    for (int e = 0; e < 4; e++) av[t + e * 256] = attn_vec[(size_t)m * DMODEL + t + e * 256];
    __syncthreads();
    float acc[4] = {0.f, 0.f, 0.f, 0.f};
    for (int k = 0; k < DMODEL; k++) {
        float a = av[k];
        #pragma unroll
        for (int e = 0; e < 4; e++)
            acc[e] = fmaf(a, W_o[(size_t)k * DMODEL + e * 256 + t], acc[e]);
    }
    float x[4];
    #pragma unroll
    for (int e = 0; e < 4; e++)
        x[e] = acc[e] + w[(size_t)m * DMODEL + e * 256 + t];

    float s = x[0] + x[1] + x[2] + x[3];
    red[t] = s;
    __syncthreads();
    #pragma unroll
    for (int off = 128; off; off >>= 1) {
        if (t < off) red[t] += red[t + off];
        __syncthreads();
    }
    const float mu = red[0] * (1.f / 1024.f);
    __syncthreads();
    float s2 = 0.f;
    #pragma unroll
    for (int e = 0; e < 4; e++) { float dx = x[e] - mu; s2 += dx * dx; }
    red[t] = s2;
    __syncthreads();
    #pragma unroll
    for (int off = 128; off; off >>= 1) {
        if (t < off) red[t] += red[t + off];
        __syncthreads();
    }
    const float rstd = rsqrtf(red[0] * (1.f / 1024.f) + LN_EPS);
    #pragma unroll
    for (int e = 0; e < 4; e++) {
        int c = e * 256 + t;
        out[(size_t)m * DMODEL + c] = (x[e] - mu) * rstd * gamma[c] + beta[c];
    }
}

extern "C" void kernel_launch(void* const* d_in, const int* in_sizes, int n_in,
                              void* d_out, int out_size, void* d_ws, size_t ws_size,
                              hipStream_t stream) {
    const float* w        = (const float*)d_in[0];
    const float* r        = (const float*)d_in[1];
    const float* r_w_bias = (const float*)d_in[2];
    const float* r_r_bias = (const float*)d_in[3];
    const float* mems     = (const float*)d_in[4];
    // d_in[5] attn_mask: deterministic (j <= i+MEMLEN), applied analytically
    const float* W_qkv    = (const float*)d_in[6];
    const float* W_r      = (const float*)d_in[7];
    const float* W_o      = (const float*)d_in[8];
    const float* gamma    = (const float*)d_in[9];
    const float* beta     = (const float*)d_in[10];
    float* out = (float*)d_out;

    // Workspace (46.2 MB): all bf16 except attn_vec
    bf16* Qw = (bf16*)d_ws;                       // [2048,1024]
    bf16* Qr = Qw + (size_t)2048 * 1024;          // [2048,1024]
    bf16* Kb = Qr + (size_t)2048 * 1024;          // [4096,1024] rows j*2+b
    bf16* Vb = Kb + (size_t)4096 * 1024;          // [4096,1024]
    bf16* Vt = Vb + (size_t)4096 * 1024;          // [2048,2048] rows d*2+b
    bf16* Rk = Vt + (size_t)2048 * 2048;          // [2048,1024]
    float* attn_vec = (float*)(Rk + (size_t)2048 * 1024);  // [2048,1024] f32

    dim3 b256(256);
    gemm_qkv<<<dim3(64, 48), b256, 0, stream>>>(
        mems, w, W_qkv, r_w_bias, r_r_bias, Qw, Qr, Kb, Vb);
    gemm_r<<<dim3(32, 16), b256, 0, stream>>>(r, W_r, Rk);
    transpose_v<<<dim3(32, 16, 2), b256, 0, stream>>>(Vb, Vt);
    attn_mfma<<<dim3(16, 2, 16), b256, 0, stream>>>(Qw, Qr, Kb, Vt, Rk, attn_vec);
    outproj_ln<<<dim3(QLEN * BSZ), b256, 0, stream>>>(
        attn_vec, W_o, w, gamma, beta, out);
}

// Round 6
// 412.001 us; speedup vs baseline: 11.3482x; 2.7989x over previous
//
#include <hip/hip_runtime.h>
#include <hip/hip_bf16.h>

#define NHEAD 16
#define DHEAD 64
#define DMODEL 1024
#define QLEN 1024
#define MEMLEN 1024
#define BSZ 2
#define KLEN 2048
#define LN_EPS 1e-5f

typedef __hip_bfloat16 bf16;
typedef __attribute__((ext_vector_type(8))) short short8;
typedef __attribute__((ext_vector_type(4))) float f32x4;

__device__ __forceinline__ bf16 f2b(float x) { return __float2bfloat16(x); }
__device__ __forceinline__ short f2bs(float f) {
    bf16 h = __float2bfloat16(f);
    return *reinterpret_cast<short*>(&h);
}

#define MFMA16(a, b, c) __builtin_amdgcn_mfma_f32_16x16x32_bf16(a, b, c, 0, 0, 0)

// ---------------- f32 -> bf16 flat convert ----------------
__global__ __launch_bounds__(256)
void conv_bf16(const float* __restrict__ src, bf16* __restrict__ dst, int n4) {
    int i = blockIdx.x * 256 + threadIdx.x;
    if (i < n4) {
        const float4 v = reinterpret_cast<const float4*>(src)[i];
        bf16 o[4] = {f2b(v.x), f2b(v.y), f2b(v.z), f2b(v.w)};
        reinterpret_cast<ulong1*>(dst)[i] = *reinterpret_cast<ulong1*>(o);
    }
}

// ---------------- f32 [K][N] -> bf16 [N][K] transpose-convert ----------------
__global__ __launch_bounds__(256)
void conv_wT(const float* __restrict__ in, bf16* __restrict__ out, int K, int N) {
    __shared__ bf16 T[64][65];
    const int n0 = blockIdx.x * 64, k0 = blockIdx.y * 64;
    const int t = threadIdx.x;
    #pragma unroll
    for (int e = 0; e < 16; e++) {
        int flat = e * 256 + t;
        int kl = flat >> 6, nl = flat & 63;
        T[kl][nl] = f2b(in[(size_t)(k0 + kl) * N + n0 + nl]);
    }
    __syncthreads();
    #pragma unroll
    for (int e = 0; e < 16; e++) {
        int flat = e * 256 + t;
        int nl = flat >> 6, kl = flat & 63;
        out[(size_t)(n0 + nl) * K + k0 + kl] = T[kl][nl];
    }
}

// ---------------- MFMA GEMM: C[M,N] = A[M,K](bf16) @ Bt[N,K](bf16)^T ----------------
// 128x128 tile, BK=32, 4 waves in 2x2, each wave 64x64 (4x4 MFMA 16x16x32 tiles).
// Frag layouts (verified): A[m=l16][k=quad*8+j]; B^T row n contiguous; C/D col=l16,row=quad*4+r.
// mode 0: QKV epilogue (N=3072; seg0 -> Qw/Qr with bias, rows m>=2048 only; seg1 -> Kb; seg2 -> Vb)
// mode 1: bf16 store to Cb; mode 2: f32 store to Cf.
__global__ __launch_bounds__(256)
void gemm_mfma(const bf16* __restrict__ A, const bf16* __restrict__ Bt,
               int M, int N, int K, int mode,
               const float* __restrict__ rwb, const float* __restrict__ rrb,
               bf16* __restrict__ Qw, bf16* __restrict__ Qr,
               bf16* __restrict__ Kb, bf16* __restrict__ Vb,
               bf16* __restrict__ Cb, float* __restrict__ Cf) {
    const int bm = blockIdx.x * 128, bn = blockIdx.y * 128;
    if (mode == 0 && bm < 2048 && bn < 1024) return;  // Q of mem rows: never used
    __shared__ bf16 As[128 * 40];   // rows 128, K-chunk 32 padded to 40
    __shared__ bf16 Bs[128 * 40];
    const int t = threadIdx.x;
    const int w = t >> 6, lane = t & 63, quad = lane >> 4, l16 = lane & 15;
    const int wm = (w >> 1) * 64, wn = (w & 1) * 64;

    f32x4 acc[4][4];
    #pragma unroll
    for (int mt = 0; mt < 4; mt++)
        #pragma unroll
        for (int nt = 0; nt < 4; nt++) acc[mt][nt] = (f32x4){0.f, 0.f, 0.f, 0.f};

    for (int k0 = 0; k0 < K; k0 += 32) {
        #pragma unroll
        for (int e = 0; e < 2; e++) {
            int c = t + e * 256;          // chunk: row = c>>2, kc = (c&3)*8
            int row = c >> 2, kc = (c & 3) * 8;
            *reinterpret_cast<short8*>(&As[row * 40 + kc]) =
                *reinterpret_cast<const short8*>(&A[(size_t)(bm + row) * K + k0 + kc]);
            *reinterpret_cast<short8*>(&Bs[row * 40 + kc]) =
                *reinterpret_cast<const short8*>(&Bt[(size_t)(bn + row) * K + k0 + kc]);
        }
        __syncthreads();
        short8 af[4], bfr[4];
        #pragma unroll
        for (int mt = 0; mt < 4; mt++)
            af[mt] = *reinterpret_cast<short8*>(&As[(wm + 16 * mt + l16) * 40 + quad * 8]);
        #pragma unroll
        for (int nt = 0; nt < 4; nt++)
            bfr[nt] = *reinterpret_cast<short8*>(&Bs[(wn + 16 * nt + l16) * 40 + quad * 8]);
        #pragma unroll
        for (int mt = 0; mt < 4; mt++)
            #pragma unroll
            for (int nt = 0; nt < 4; nt++)
                acc[mt][nt] = MFMA16(af[mt], bfr[nt], acc[mt][nt]);
        __syncthreads();
    }

    #pragma unroll
    for (int mt = 0; mt < 4; mt++)
        #pragma unroll
        for (int nt = 0; nt < 4; nt++)
            #pragma unroll
            for (int r = 0; r < 4; r++) {
                int m = bm + wm + 16 * mt + quad * 4 + r;
                int c = bn + wn + 16 * nt + l16;
                float v = acc[mt][nt][r];
                if (mode == 0) {
                    int seg = c >> 10, cc = c & 1023;
                    if (seg == 0) {
                        if (m >= 2048) {
                            size_t o = (size_t)(m - 2048) * 1024 + cc;
                            Qw[o] = f2b(v + rwb[cc]);
                            Qr[o] = f2b(v + rrb[cc]);
                        }
                    } else if (seg == 1) Kb[(size_t)m * 1024 + cc] = f2b(v);
                    else                 Vb[(size_t)m * 1024 + cc] = f2b(v);
                } else if (mode == 1) Cb[(size_t)m * N + c] = f2b(v);
                else                  Cf[(size_t)m * N + c] = v;
            }
}

// ---------------- V transpose: Vb[j*2+b][d] -> Vt[(d*2+b)][j] ----------------
__global__ __launch_bounds__(256)
void transpose_v(const bf16* __restrict__ Vb, bf16* __restrict__ Vt) {
    __shared__ bf16 T[64][65];
    const int J0 = blockIdx.x * 64, D0 = blockIdx.y * 64, b = blockIdx.z;
    const int t = threadIdx.x;
    #pragma unroll
    for (int e = 0; e < 16; e++) {
        int flat = e * 256 + t;
        int jl = flat >> 6, dl = flat & 63;
        T[jl][dl] = Vb[(size_t)((J0 + jl) * 2 + b) * 1024 + D0 + dl];
    }
    __syncthreads();
    #pragma unroll
    for (int e = 0; e < 16; e++) {
        int flat = e * 256 + t;
        int dl = flat >> 6, jl = flat & 63;
        Vt[(size_t)((D0 + dl) * 2 + b) * 2048 + J0 + jl] = T[jl][dl];
    }
}

// ---------------- MFMA flash attention (R5-verified), bf16 output ----------------
__global__ __launch_bounds__(256)
void attn_mfma(const bf16* __restrict__ Qw, const bf16* __restrict__ Qr,
               const bf16* __restrict__ Kb, const bf16* __restrict__ Vt,
               const bf16* __restrict__ Rk, bf16* __restrict__ attn_vec) {
    const int I0 = blockIdx.x * 64, b = blockIdx.y, n = blockIdx.z;
    const int tid = threadIdx.x;
    const int w = tid >> 6, lane = tid & 63;
    const int quad = lane >> 4, l16 = lane & 15;
    const int qbase = I0 + 16 * w;

    __shared__ float Wl_s[4][16 * 80];
    __shared__ float Pl_s[4][16 * 68];
    float* Wl = Wl_s[w];
    float* Pl = Pl_s[w];

    short8 aqw[2], aqr[2];
    {
        const bf16* qp = Qw + ((size_t)(qbase + l16) * 2 + b) * 1024 + n * 64 + quad * 8;
        aqw[0] = *reinterpret_cast<const short8*>(qp);
        aqw[1] = *reinterpret_cast<const short8*>(qp + 32);
        const bf16* qp2 = Qr + ((size_t)(qbase + l16) * 2 + b) * 1024 + n * 64 + quad * 8;
        aqr[0] = *reinterpret_cast<const short8*>(qp2);
        aqr[1] = *reinterpret_cast<const short8*>(qp2 + 32);
    }

    f32x4 O[4];
    #pragma unroll
    for (int d = 0; d < 4; d++) O[d] = (f32x4){0.f, 0.f, 0.f, 0.f};
    float m_r[4], l_r[4];
    #pragma unroll
    for (int r = 0; r < 4; r++) { m_r[r] = -1e30f; l_r[r] = 0.f; }

    const int Jmax = qbase + 15 + MEMLEN;
    for (int J0 = 0; J0 <= Jmax; J0 += 64) {
        const int Rw0 = J0 - qbase + 1008;
        #pragma unroll
        for (int s = 0; s < 5; s++) {
            int rrow = Rw0 + 16 * s + l16;
            short8 b0 = (short8){0,0,0,0,0,0,0,0}, b1 = b0;
            if (rrow < 2048) {
                const bf16* rp = Rk + (size_t)rrow * 1024 + n * 64 + quad * 8;
                b0 = *reinterpret_cast<const short8*>(rp);
                b1 = *reinterpret_cast<const short8*>(rp + 32);
            }
            f32x4 acc = (f32x4){0.f, 0.f, 0.f, 0.f};
            acc = MFMA16(aqr[0], b0, acc);
            acc = MFMA16(aqr[1], b1, acc);
            #pragma unroll
            for (int r = 0; r < 4; r++)
                Wl[(quad * 4 + r) * 80 + 16 * s + l16] = acc[r];
        }

        float sv[4][4];
        #pragma unroll
        for (int n16 = 0; n16 < 4; n16++) {
            int key = J0 + 16 * n16 + l16;
            const bf16* kp = Kb + ((size_t)key * 2 + b) * 1024 + n * 64 + quad * 8;
            short8 k0 = *reinterpret_cast<const short8*>(kp);
            short8 k1 = *reinterpret_cast<const short8*>(kp + 32);
            f32x4 acc = (f32x4){0.f, 0.f, 0.f, 0.f};
            acc = MFMA16(aqw[0], k0, acc);
            acc = MFMA16(aqw[1], k1, acc);
            #pragma unroll
            for (int r = 0; r < 4; r++) {
                int row = quad * 4 + r, col = 16 * n16 + l16;
                float s = (acc[r] + Wl[row * 80 + col - row + 15]) * 0.125f;
                if (J0 + col > qbase + row + MEMLEN) s = -1e30f;
                sv[n16][r] = s;
            }
        }

        float alpha[4];
        #pragma unroll
        for (int r = 0; r < 4; r++) {
            float mx = fmaxf(fmaxf(sv[0][r], sv[1][r]), fmaxf(sv[2][r], sv[3][r]));
            #pragma unroll
            for (int msk = 1; msk < 16; msk <<= 1) mx = fmaxf(mx, __shfl_xor(mx, msk));
            float mn = fmaxf(m_r[r], mx);
            alpha[r] = __expf(m_r[r] - mn);
            m_r[r] = mn;
            float rs = 0.f;
            #pragma unroll
            for (int n16 = 0; n16 < 4; n16++) {
                float p = __expf(sv[n16][r] - mn);
                sv[n16][r] = p;
                rs += p;
            }
            #pragma unroll
            for (int msk = 1; msk < 16; msk <<= 1) rs += __shfl_xor(rs, msk);
            l_r[r] = l_r[r] * alpha[r] + rs;
        }

        #pragma unroll
        for (int n16 = 0; n16 < 4; n16++)
            #pragma unroll
            for (int r = 0; r < 4; r++)
                Pl[(quad * 4 + r) * 68 + 16 * n16 + l16] = sv[n16][r];
        #pragma unroll
        for (int d = 0; d < 4; d++)
            #pragma unroll
            for (int r = 0; r < 4; r++)
                O[d][r] *= alpha[r];

        short8 ap[2];
        #pragma unroll
        for (int kc = 0; kc < 2; kc++) {
            short8 v;
            #pragma unroll
            for (int j = 0; j < 8; j++)
                v[j] = f2bs(Pl[l16 * 68 + kc * 32 + quad * 8 + j]);
            ap[kc] = v;
        }

        #pragma unroll
        for (int ds = 0; ds < 4; ds++) {
            const bf16* vp = Vt + ((size_t)(n * 64 + 16 * ds + l16) * 2 + b) * 2048
                             + J0 + quad * 8;
            short8 v0 = *reinterpret_cast<const short8*>(vp);
            short8 v1 = *reinterpret_cast<const short8*>(vp + 32);
            O[ds] = MFMA16(ap[0], v0, O[ds]);
            O[ds] = MFMA16(ap[1], v1, O[ds]);
        }
    }

    #pragma unroll
    for (int ds = 0; ds < 4; ds++)
        #pragma unroll
        for (int r = 0; r < 4; r++) {
            int q = qbase + quad * 4 + r;
            attn_vec[((size_t)q * 2 + b) * 1024 + n * 64 + 16 * ds + l16] =
                f2b(O[ds][r] / l_r[r]);
        }
}

// ---------------- out = LN(w + attn_out), f32 ----------------
__global__ __launch_bounds__(256)
void ln_res(const float* __restrict__ ao, const float* __restrict__ w,
            const float* __restrict__ gamma, const float* __restrict__ beta,
            float* __restrict__ out) {
    const int m = blockIdx.x;
    const int t = threadIdx.x;
    __shared__ float red[256];
    float x[4];
    #pragma unroll
    for (int e = 0; e < 4; e++) {
        int c = e * 256 + t;
        x[e] = ao[(size_t)m * DMODEL + c] + w[(size_t)m * DMODEL + c];
    }
    float s = x[0] + x[1] + x[2] + x[3];
    red[t] = s;
    __syncthreads();
    #pragma unroll
    for (int off = 128; off; off >>= 1) {
        if (t < off) red[t] += red[t + off];
        __syncthreads();
    }
    const float mu = red[0] * (1.f / 1024.f);
    __syncthreads();
    float s2 = 0.f;
    #pragma unroll
    for (int e = 0; e < 4; e++) { float dx = x[e] - mu; s2 += dx * dx; }
    red[t] = s2;
    __syncthreads();
    #pragma unroll
    for (int off = 128; off; off >>= 1) {
        if (t < off) red[t] += red[t + off];
        __syncthreads();
    }
    const float rstd = rsqrtf(red[0] * (1.f / 1024.f) + LN_EPS);
    #pragma unroll
    for (int e = 0; e < 4; e++) {
        int c = e * 256 + t;
        out[(size_t)m * DMODEL + c] = (x[e] - mu) * rstd * gamma[c] + beta[c];
    }
}

extern "C" void kernel_launch(void* const* d_in, const int* in_sizes, int n_in,
                              void* d_out, int out_size, void* d_ws, size_t ws_size,
                              hipStream_t stream) {
    const float* w        = (const float*)d_in[0];
    const float* r        = (const float*)d_in[1];
    const float* r_w_bias = (const float*)d_in[2];
    const float* r_r_bias = (const float*)d_in[3];
    const float* mems     = (const float*)d_in[4];
    // d_in[5] attn_mask: deterministic (j <= i+MEMLEN), applied analytically
    const float* W_qkv    = (const float*)d_in[6];
    const float* W_r      = (const float*)d_in[7];
    const float* W_o      = (const float*)d_in[8];
    const float* gamma    = (const float*)d_in[9];
    const float* beta     = (const float*)d_in[10];
    float* out = (float*)d_out;

    // Workspace (64.9 MB). attn_out (f32, 8.4MB) aliases Abf (dead after GEMM1).
    bf16* Abf    = (bf16*)d_ws;                    // [4096,1024] cat rows m=j*2+b
    bf16* Wqkvt  = Abf   + (size_t)4096 * 1024;    // [3072,1024]
    bf16* Wrt    = Wqkvt + (size_t)3072 * 1024;    // [1024,1024]
    bf16* Wot    = Wrt   + (size_t)1024 * 1024;    // [1024,1024]
    bf16* rbf    = Wot   + (size_t)1024 * 1024;    // [2048,1024]
    bf16* Qw     = rbf   + (size_t)2048 * 1024;    // [2048,1024] rows i*2+b
    bf16* Qr     = Qw    + (size_t)2048 * 1024;
    bf16* Kb     = Qr    + (size_t)2048 * 1024;    // [4096,1024] rows j*2+b
    bf16* Vb     = Kb    + (size_t)4096 * 1024;
    bf16* Vt     = Vb    + (size_t)4096 * 1024;    // [2048,2048] rows d*2+b
    bf16* Rk     = Vt    + (size_t)2048 * 2048;    // [2048,1024]
    bf16* AVbf   = Rk    + (size_t)2048 * 1024;    // [2048,1024] attn vec bf16
    float* attn_out = (float*)Abf;                 // [2048,1024] f32 (alias)

    dim3 b256(256);
    // converts
    conv_bf16<<<dim3(2048), b256, 0, stream>>>(mems, Abf, 2048 * 256);
    conv_bf16<<<dim3(2048), b256, 0, stream>>>(w, Abf + (size_t)2048 * 1024, 2048 * 256);
    conv_bf16<<<dim3(2048), b256, 0, stream>>>(r, rbf, 2048 * 256);
    conv_wT<<<dim3(48, 16), b256, 0, stream>>>(W_qkv, Wqkvt, 1024, 3072);
    conv_wT<<<dim3(16, 16), b256, 0, stream>>>(W_r, Wrt, 1024, 1024);
    conv_wT<<<dim3(16, 16), b256, 0, stream>>>(W_o, Wot, 1024, 1024);
    // QKV projection (MFMA)
    gemm_mfma<<<dim3(32, 24), b256, 0, stream>>>(
        Abf, Wqkvt, 4096, 3072, 1024, 0, r_w_bias, r_r_bias,
        Qw, Qr, Kb, Vb, nullptr, nullptr);
    // Rk = r @ W_r (MFMA)
    gemm_mfma<<<dim3(16, 8), b256, 0, stream>>>(
        rbf, Wrt, 2048, 1024, 1024, 1, nullptr, nullptr,
        nullptr, nullptr, nullptr, nullptr, Rk, nullptr);
    transpose_v<<<dim3(32, 16, 2), b256, 0, stream>>>(Vb, Vt);
    attn_mfma<<<dim3(16, 2, 16), b256, 0, stream>>>(Qw, Qr, Kb, Vt, Rk, AVbf);
    // attn_out = attn_vec @ W_o (MFMA)
    gemm_mfma<<<dim3(16, 8), b256, 0, stream>>>(
        AVbf, Wot, 2048, 1024, 1024, 2, nullptr, nullptr,
        nullptr, nullptr, nullptr, nullptr, nullptr, attn_out);
    ln_res<<<dim3(QLEN * BSZ), b256, 0, stream>>>(attn_out, w, gamma, beta, out);
}